// Round 1
// baseline (331.632 us; speedup 1.0000x reference)
//
#include <hip/hip_runtime.h>

#define NBATCH 512
#define NS 66
#define ND 304
#define NK 128
#define TPAD 132   // padded LDS row stride (floats): breaks stride-128 bank conflict

__global__ __launch_bounds__(256) void treeprobe_kernel(
    const float* __restrict__ x,   // [512][66][304]
    const float* __restrict__ W,   // [128][304]
    float* __restrict__ out)       // [512][66][66]
{
    __shared__ float ts[NS][TPAD];           // 66*132*4 = 34848 B

    const int tid   = threadIdx.x;
    const int batch = blockIdx.x;
    const int k     = tid & (NK - 1);        // 0..127 : output column of t
    const int sg    = tid >> 7;              // 0,1    : s parity group
    const float* __restrict__ xb = x + (size_t)batch * NS * ND;

    // ---------------- Phase 1: t[s][k] = dot(x[s,:], W[k,:]) ----------------
    // (bias b cancels in the pairwise difference; skip it)
    float acc[33];
#pragma unroll
    for (int i = 0; i < 33; ++i) acc[i] = 0.f;

    const float* __restrict__ wrow = W + (size_t)k * ND;
    for (int d = 0; d < ND; d += 4) {
        const float4 wv = *reinterpret_cast<const float4*>(wrow + d);
#pragma unroll
        for (int i = 0; i < 33; ++i) {
            const int s = sg + 2 * i;
            const float4 xv = *reinterpret_cast<const float4*>(xb + s * ND + d);
            acc[i] += wv.x * xv.x;
            acc[i] += wv.y * xv.y;
            acc[i] += wv.z * xv.z;
            acc[i] += wv.w * xv.w;
        }
    }
#pragma unroll
    for (int i = 0; i < 33; ++i) {
        ts[sg + 2 * i][k] = acc[i];
    }
    __syncthreads();

    // ------------- Phase 2: out[i][j] = sum_k (t[i][k]-t[j][k])^2 -----------
    // 2x2 register blocking over (i,j): 33x33 blocks cover the full 66x66.
    float* __restrict__ ob = out + (size_t)batch * NS * NS;

    for (int bidx = tid; bidx < 33 * 33; bidx += 256) {
        const int bi = (bidx / 33) * 2;
        const int bj = (bidx % 33) * 2;
        float s00 = 0.f, s01 = 0.f, s10 = 0.f, s11 = 0.f;
#pragma unroll
        for (int k4 = 0; k4 < NK; k4 += 4) {
            const float4 a0 = *reinterpret_cast<const float4*>(&ts[bi][k4]);
            const float4 a1 = *reinterpret_cast<const float4*>(&ts[bi + 1][k4]);
            const float4 c0 = *reinterpret_cast<const float4*>(&ts[bj][k4]);
            const float4 c1 = *reinterpret_cast<const float4*>(&ts[bj + 1][k4]);

            float d;
            d = a0.x - c0.x; s00 += d * d;
            d = a0.y - c0.y; s00 += d * d;
            d = a0.z - c0.z; s00 += d * d;
            d = a0.w - c0.w; s00 += d * d;

            d = a0.x - c1.x; s01 += d * d;
            d = a0.y - c1.y; s01 += d * d;
            d = a0.z - c1.z; s01 += d * d;
            d = a0.w - c1.w; s01 += d * d;

            d = a1.x - c0.x; s10 += d * d;
            d = a1.y - c0.y; s10 += d * d;
            d = a1.z - c0.z; s10 += d * d;
            d = a1.w - c0.w; s10 += d * d;

            d = a1.x - c1.x; s11 += d * d;
            d = a1.y - c1.y; s11 += d * d;
            d = a1.z - c1.z; s11 += d * d;
            d = a1.w - c1.w; s11 += d * d;
        }
        ob[(size_t)bi * NS + bj]           = s00;
        ob[(size_t)bi * NS + bj + 1]       = s01;
        ob[(size_t)(bi + 1) * NS + bj]     = s10;
        ob[(size_t)(bi + 1) * NS + bj + 1] = s11;
    }
}

extern "C" void kernel_launch(void* const* d_in, const int* in_sizes, int n_in,
                              void* d_out, int out_size, void* d_ws, size_t ws_size,
                              hipStream_t stream) {
    const float* x = (const float*)d_in[0];   // (512, 66, 304) f32
    const float* W = (const float*)d_in[1];   // (128, 304) f32
    // d_in[2] = b : cancels in pairwise differences, unused.
    float* out = (float*)d_out;               // (512, 66, 66) f32

    treeprobe_kernel<<<NBATCH, 256, 0, stream>>>(x, W, out);
}

// Round 2
// 23.882 us; speedup vs baseline: 13.8860x; 13.8860x over previous
//
#include <hip/hip_runtime.h>
#include <hip/hip_bf16.h>

#define NBATCH 512
#define NS 66
#define ND 304
#define NK 128

#define XROWS 80           // 5 M-tiles of 16 (rows 66..79 zero)
#define XSTRIDE_B 640      // 320 bf16 per row (K padded 304->320)
#define XBYTES (XROWS * XSTRIDE_B)          // 51200
#define TSTRIDE_B 256      // 128 bf16 per row
#define TBYTES (XROWS * TSTRIDE_B)          // 20480
#define GSTRIDE 84         // floats per G row (80x84 f32 = 26880 B, overlays x)

typedef __attribute__((ext_vector_type(8))) short bf16x8;
typedef __attribute__((ext_vector_type(4))) short s16x4;
typedef __attribute__((ext_vector_type(4))) float f32x4;

__device__ __forceinline__ short f2bf(float x) {
    return __builtin_bit_cast(short, __float2bfloat16(x));
}

__global__ __launch_bounds__(256, 2) void treeprobe_mfma(
    const float* __restrict__ x,   // [512][66][304]
    const float* __restrict__ W,   // [128][304]
    float* __restrict__ out)       // [512][66][66]
{
    // LDS: [x_bf16 swizzled | t_bf16 swizzled], G(f32) overlays x after phase 1.
    __shared__ __align__(16) char lds[XBYTES + TBYTES];
    char* const t_lds = lds + XBYTES;
    float* const G = (float*)lds;

    const int tid   = threadIdx.x;
    const int batch = blockIdx.x;
    const int lane  = tid & 63;
    const int wv    = tid >> 6;     // wave 0..3
    const int lr    = lane & 15;    // fragment row/col within 16
    const int lg    = lane >> 4;    // k-group 0..3

    // ---- W fragments -> registers (once per block; W is L2/L3-resident) ----
    // B-frag for 16x16x32: col = lane&15, k = kk*32 + (lane>>4)*8 + i (8 contiguous)
    bf16x8 wfrag[2][10];
#pragma unroll
    for (int nt = 0; nt < 2; ++nt) {
        const int c = (wv * 2 + nt) * 16 + lr;          // W row 0..127
        const float* __restrict__ wr = W + c * ND;
#pragma unroll
        for (int kk = 0; kk < 10; ++kk) {
            const int k0 = kk * 32 + lg * 8;
            bf16x8 f = {0, 0, 0, 0, 0, 0, 0, 0};
            if (k0 < ND) {
                const float4 p0 = *reinterpret_cast<const float4*>(wr + k0);
                const float4 p1 = *reinterpret_cast<const float4*>(wr + k0 + 4);
                f[0] = f2bf(p0.x); f[1] = f2bf(p0.y);
                f[2] = f2bf(p0.z); f[3] = f2bf(p0.w);
                f[4] = f2bf(p1.x); f[5] = f2bf(p1.y);
                f[6] = f2bf(p1.z); f[7] = f2bf(p1.w);
            }
            wfrag[nt][kk] = f;
        }
    }

    // ---- zero-fill x region (pad rows 66..79 and k 304..319 must be 0) ----
    for (int i = tid; i < XBYTES / 16; i += 256) {
        *reinterpret_cast<f32x4*>(lds + i * 16) = (f32x4){0.f, 0.f, 0.f, 0.f};
    }
    __syncthreads();

    // ---- stage x -> bf16 LDS, XOR-swizzled (byte ^= (row&7)<<4) ----
    const float* __restrict__ xb = x + (size_t)batch * NS * ND;
    for (int e = tid; e < NS * ND / 4; e += 256) {      // 5016 float4
        const int s  = e / 76;                          // ND/4 = 76
        const int d4 = (e % 76) * 4;
        const float4 v = *reinterpret_cast<const float4*>(xb + e * 4);
        int byte = s * XSTRIDE_B + d4 * 2;
        byte ^= (s & 7) << 4;
        s16x4 sv;
        sv[0] = f2bf(v.x); sv[1] = f2bf(v.y);
        sv[2] = f2bf(v.z); sv[3] = f2bf(v.w);
        *reinterpret_cast<s16x4*>(lds + byte) = sv;
    }
    __syncthreads();

    // ---- Phase 1: t[s][c] = sum_d x[s][d] * W[c][d]  (5 Mtiles x 2 Ntiles/wave)
    f32x4 acc[5][2];
#pragma unroll
    for (int mt = 0; mt < 5; ++mt)
#pragma unroll
        for (int nt = 0; nt < 2; ++nt)
            acc[mt][nt] = (f32x4){0.f, 0.f, 0.f, 0.f};

#pragma unroll
    for (int kk = 0; kk < 10; ++kk) {
        bf16x8 a[5];
#pragma unroll
        for (int mt = 0; mt < 5; ++mt) {
            const int row = mt * 16 + lr;
            int byte = row * XSTRIDE_B + kk * 64 + lg * 16;
            byte ^= (row & 7) << 4;
            a[mt] = *reinterpret_cast<const bf16x8*>(lds + byte);
        }
#pragma unroll
        for (int mt = 0; mt < 5; ++mt)
#pragma unroll
            for (int nt = 0; nt < 2; ++nt)
                acc[mt][nt] = __builtin_amdgcn_mfma_f32_16x16x32_bf16(
                    a[mt], wfrag[nt][kk], acc[mt][nt], 0, 0, 0);
    }

    // ---- write t (bf16, swizzled). D layout: col=lane&15, row=(lane>>4)*4+reg
#pragma unroll
    for (int mt = 0; mt < 5; ++mt)
#pragma unroll
        for (int nt = 0; nt < 2; ++nt) {
            const int col = (wv * 2 + nt) * 16 + lr;
#pragma unroll
            for (int r = 0; r < 4; ++r) {
                const int row = mt * 16 + lg * 4 + r;
                int byte = row * TSTRIDE_B + col * 2;
                byte ^= (row & 7) << 4;
                *reinterpret_cast<short*>(t_lds + byte) = f2bf(acc[mt][nt][r]);
            }
        }
    __syncthreads();

    // ---- Phase 2: G = t . t^T  (25 tiles of 16x16, K=128 = 4 steps) ----
    for (int tile = wv; tile < 25; tile += 4) {
        const int ti = tile / 5, tj = tile % 5;
        f32x4 g = (f32x4){0.f, 0.f, 0.f, 0.f};
#pragma unroll
        for (int kk = 0; kk < 4; ++kk) {
            const int ra = ti * 16 + lr;
            int ba = ra * TSTRIDE_B + kk * 64 + lg * 16;
            ba ^= (ra & 7) << 4;
            const int rb = tj * 16 + lr;
            int bb = rb * TSTRIDE_B + kk * 64 + lg * 16;
            bb ^= (rb & 7) << 4;
            const bf16x8 av = *reinterpret_cast<const bf16x8*>(t_lds + ba);
            const bf16x8 bv = *reinterpret_cast<const bf16x8*>(t_lds + bb);
            g = __builtin_amdgcn_mfma_f32_16x16x32_bf16(av, bv, g, 0, 0, 0);
        }
#pragma unroll
        for (int r = 0; r < 4; ++r) {
            const int row = ti * 16 + lg * 4 + r;
            const int col = tj * 16 + lr;
            G[row * GSTRIDE + col] = g[r];
        }
    }
    __syncthreads();

    // ---- out[i][j] = G[i][i] + G[j][j] - 2 G[i][j] ----
    float* __restrict__ ob = out + (size_t)batch * NS * NS;
    for (int e = tid; e < NS * NS / 2; e += 256) {      // 2178 float2
        const int i = e / 33;
        const int j = (e % 33) * 2;
        const float nii = G[i * GSTRIDE + i];
        float2 r;
        r.x = nii + G[j * GSTRIDE + j] - 2.f * G[i * GSTRIDE + j];
        r.y = nii + G[(j + 1) * GSTRIDE + (j + 1)] - 2.f * G[i * GSTRIDE + j + 1];
        *reinterpret_cast<float2*>(ob + i * NS + j) = r;
    }
}

extern "C" void kernel_launch(void* const* d_in, const int* in_sizes, int n_in,
                              void* d_out, int out_size, void* d_ws, size_t ws_size,
                              hipStream_t stream) {
    const float* x = (const float*)d_in[0];   // (512, 66, 304) f32
    const float* W = (const float*)d_in[1];   // (128, 304) f32
    // d_in[2] = b : cancels in the pairwise difference, unused.
    float* out = (float*)d_out;               // (512, 66, 66) f32

    treeprobe_mfma<<<NBATCH, 256, 0, stream>>>(x, W, out);
}

// Round 3
// 21.264 us; speedup vs baseline: 15.5963x; 1.1232x over previous
//
#include <hip/hip_runtime.h>
#include <hip/hip_bf16.h>

#define NBATCH 512
#define NS 66
#define ND 304
#define NK 128

#define XROWS 80           // 5 M-tiles of 16 (rows 66..79 zero)
#define XSTRIDE_B 640      // 320 bf16 per row (K padded 304->320)
#define XBYTES (XROWS * XSTRIDE_B)          // 51200
#define TSTRIDE_B 256      // 128 bf16 per row
#define TBYTES (XROWS * TSTRIDE_B)          // 20480
#define GSTRIDE 84         // floats per G row (80x84 f32 = 26880 B, overlays x)

#define NTHREADS 512       // 8 waves: 1 N-tile (16 cols) per wave

typedef __attribute__((ext_vector_type(8))) short bf16x8;
typedef __attribute__((ext_vector_type(4))) short s16x4;
typedef __attribute__((ext_vector_type(4))) float f32x4;

__device__ __forceinline__ short f2bf(float x) {
    return __builtin_bit_cast(short, __float2bfloat16(x));
}

__global__ __launch_bounds__(NTHREADS, 4) void treeprobe_mfma(
    const float* __restrict__ x,   // [512][66][304]
    const float* __restrict__ W,   // [128][304]
    float* __restrict__ out)       // [512][66][66]
{
    // LDS: [x_bf16 swizzled | t_bf16 swizzled], G(f32) overlays x after phase 1.
    __shared__ __align__(16) char lds[XBYTES + TBYTES];
    char* const t_lds = lds + XBYTES;
    float* const G = (float*)lds;

    const int tid   = threadIdx.x;
    const int batch = blockIdx.x;
    const int lane  = tid & 63;
    const int wv    = tid >> 6;     // wave 0..7
    const int lr    = lane & 15;    // fragment row/col within 16
    const int lg    = lane >> 4;    // k-group 0..3

    // ---- W fragments -> registers (1 N-tile of 16 cols per wave) ----
    // B-frag for 16x16x32: col = lane&15, k = kk*32 + (lane>>4)*8 + i (8 contiguous)
    bf16x8 wfrag[10];
    {
        const int c = wv * 16 + lr;                     // W row 0..127
        const float* __restrict__ wr = W + c * ND;
#pragma unroll
        for (int kk = 0; kk < 10; ++kk) {
            const int k0 = kk * 32 + lg * 8;
            bf16x8 f = {0, 0, 0, 0, 0, 0, 0, 0};
            if (k0 < ND) {
                const float4 p0 = *reinterpret_cast<const float4*>(wr + k0);
                const float4 p1 = *reinterpret_cast<const float4*>(wr + k0 + 4);
                f[0] = f2bf(p0.x); f[1] = f2bf(p0.y);
                f[2] = f2bf(p0.z); f[3] = f2bf(p0.w);
                f[4] = f2bf(p1.x); f[5] = f2bf(p1.y);
                f[6] = f2bf(p1.z); f[7] = f2bf(p1.w);
            }
            wfrag[kk] = f;
        }
    }

    // ---- zero-fill x region (pad rows 66..79 and k 304..319 must be 0) ----
    for (int i = tid; i < XBYTES / 16; i += NTHREADS) {
        *reinterpret_cast<f32x4*>(lds + i * 16) = (f32x4){0.f, 0.f, 0.f, 0.f};
    }
    __syncthreads();

    // ---- stage x -> bf16 LDS, XOR-swizzled (byte ^= (row&7)<<4) ----
    const float* __restrict__ xb = x + (size_t)batch * NS * ND;
    for (int e = tid; e < NS * ND / 4; e += NTHREADS) { // 5016 float4
        const int s  = e / 76;                          // ND/4 = 76
        const int d4 = (e % 76) * 4;
        const float4 v = *reinterpret_cast<const float4*>(xb + e * 4);
        int byte = s * XSTRIDE_B + d4 * 2;
        byte ^= (s & 7) << 4;
        s16x4 sv;
        sv[0] = f2bf(v.x); sv[1] = f2bf(v.y);
        sv[2] = f2bf(v.z); sv[3] = f2bf(v.w);
        *reinterpret_cast<s16x4*>(lds + byte) = sv;
    }
    __syncthreads();

    // ---- Phase 1: t[s][c] = sum_d x[s][d] * W[c][d]  (5 Mtiles x 1 Ntile/wave)
    f32x4 acc[5];
#pragma unroll
    for (int mt = 0; mt < 5; ++mt) acc[mt] = (f32x4){0.f, 0.f, 0.f, 0.f};

#pragma unroll
    for (int kk = 0; kk < 10; ++kk) {
        bf16x8 a[5];
#pragma unroll
        for (int mt = 0; mt < 5; ++mt) {
            const int row = mt * 16 + lr;
            int byte = row * XSTRIDE_B + kk * 64 + lg * 16;
            byte ^= (row & 7) << 4;
            a[mt] = *reinterpret_cast<const bf16x8*>(lds + byte);
        }
#pragma unroll
        for (int mt = 0; mt < 5; ++mt)
            acc[mt] = __builtin_amdgcn_mfma_f32_16x16x32_bf16(
                a[mt], wfrag[kk], acc[mt], 0, 0, 0);
    }

    // ---- write t (bf16, swizzled). D layout: col=lane&15, row=(lane>>4)*4+reg
    {
        const int col = wv * 16 + lr;
#pragma unroll
        for (int mt = 0; mt < 5; ++mt) {
#pragma unroll
            for (int r = 0; r < 4; ++r) {
                const int row = mt * 16 + lg * 4 + r;
                int byte = row * TSTRIDE_B + col * 2;
                byte ^= (row & 7) << 4;
                *reinterpret_cast<short*>(t_lds + byte) = f2bf(acc[mt][r]);
            }
        }
    }
    __syncthreads();

    // ---- Phase 2: G = t . t^T  (25 tiles of 16x16, K=128 = 4 steps) ----
    for (int tile = wv; tile < 25; tile += 8) {
        const int ti = tile / 5, tj = tile % 5;
        f32x4 g = (f32x4){0.f, 0.f, 0.f, 0.f};
#pragma unroll
        for (int kk = 0; kk < 4; ++kk) {
            const int ra = ti * 16 + lr;
            int ba = ra * TSTRIDE_B + kk * 64 + lg * 16;
            ba ^= (ra & 7) << 4;
            const int rb = tj * 16 + lr;
            int bb = rb * TSTRIDE_B + kk * 64 + lg * 16;
            bb ^= (rb & 7) << 4;
            const bf16x8 av = *reinterpret_cast<const bf16x8*>(t_lds + ba);
            const bf16x8 bv = *reinterpret_cast<const bf16x8*>(t_lds + bb);
            g = __builtin_amdgcn_mfma_f32_16x16x32_bf16(av, bv, g, 0, 0, 0);
        }
#pragma unroll
        for (int r = 0; r < 4; ++r) {
            const int row = ti * 16 + lg * 4 + r;
            const int col = tj * 16 + lr;
            G[row * GSTRIDE + col] = g[r];
        }
    }
    __syncthreads();

    // ---- out[i][j] = G[i][i] + G[j][j] - 2 G[i][j] ----
    float* __restrict__ ob = out + (size_t)batch * NS * NS;
    for (int e = tid; e < NS * NS / 2; e += NTHREADS) { // 2178 float2
        const int i = e / 33;
        const int j = (e % 33) * 2;
        const float nii = G[i * GSTRIDE + i];
        float2 r;
        r.x = nii + G[j * GSTRIDE + j] - 2.f * G[i * GSTRIDE + j];
        r.y = nii + G[(j + 1) * GSTRIDE + (j + 1)] - 2.f * G[i * GSTRIDE + j + 1];
        *reinterpret_cast<float2*>(ob + i * NS + j) = r;
    }
}

extern "C" void kernel_launch(void* const* d_in, const int* in_sizes, int n_in,
                              void* d_out, int out_size, void* d_ws, size_t ws_size,
                              hipStream_t stream) {
    const float* x = (const float*)d_in[0];   // (512, 66, 304) f32
    const float* W = (const float*)d_in[1];   // (128, 304) f32
    // d_in[2] = b : cancels in the pairwise difference, unused.
    float* out = (float*)d_out;               // (512, 66, 66) f32

    treeprobe_mfma<<<NBATCH, NTHREADS, 0, stream>>>(x, W, out);
}

// Round 4
// 20.816 us; speedup vs baseline: 15.9319x; 1.0215x over previous
//
#include <hip/hip_runtime.h>
#include <hip/hip_bf16.h>

#define NBATCH 512
#define NS 66
#define ND 304
#define NK 128

#define XROWS 80           // 5 s-tiles of 16 (rows 66..79 zero)
#define XSTRIDE_B 640      // 320 bf16 per row (K padded 304->320)
#define XBYTES (XROWS * XSTRIDE_B)          // 51200
#define TSTRIDE_B 256      // 128 bf16 per row
#define TBYTES (XROWS * TSTRIDE_B)          // 20480
#define NTHREADS 512       // 8 waves

typedef __attribute__((ext_vector_type(8))) short bf16x8;
typedef __attribute__((ext_vector_type(4))) short s16x4;
typedef __attribute__((ext_vector_type(4))) float f32x4;

__device__ __forceinline__ short f2bf(float x) {
    return __builtin_bit_cast(short, __float2bfloat16(x));
}

// 15 upper-triangle 16x16 tiles of G: 5 diagonal first, then 10 strict-upper.
__device__ const int TI_LUT[15] = {0,1,2,3,4, 0,0,0,0,1,1,1,2,2,3};
__device__ const int TJ_LUT[15] = {0,1,2,3,4, 1,2,3,4,2,3,4,3,4,4};

__global__ __launch_bounds__(NTHREADS, 4) void treeprobe_mfma(
    const float* __restrict__ x,   // [512][66][304]
    const float* __restrict__ W,   // [128][304]
    float* __restrict__ out)       // [512][66][66]
{
    // LDS: x_bf16 (swizzled) | t_bf16 (swizzled) | norms f32[80]
    __shared__ __align__(16) char lds[XBYTES + TBYTES + 80 * 4];
    char* const t_lds = lds + XBYTES;
    float* const norms = (float*)(lds + XBYTES + TBYTES);

    const int tid   = threadIdx.x;
    const int batch = blockIdx.x;
    const int lane  = tid & 63;
    const int wv    = tid >> 6;     // wave 0..7
    const int lr    = lane & 15;
    const int lg    = lane >> 4;    // 0..3

    const float* __restrict__ xb = x + (size_t)batch * NS * ND;

    // ---- 1) issue stage-A global loads (x cols [0,160), 66*40=2640 float4) ----
    float4 aA[6];
#pragma unroll
    for (int i = 0; i < 6; ++i) {
        const int e = tid + i * NTHREADS;
        aA[i] = (e < 2640)
            ? *reinterpret_cast<const float4*>(xb + (e / 40) * ND + (e % 40) * 4)
            : make_float4(0.f, 0.f, 0.f, 0.f);
    }

    // ---- 2) zero-fill pad regions only ----
    // rows 66..79 full width: 14*40 = 560 16B slots (swizzle-invariant: whole rows)
    for (int i = tid; i < 560; i += NTHREADS) {
        const int row = 66 + i / 40;
        *reinterpret_cast<f32x4*>(lds + row * XSTRIDE_B + (i % 40) * 16) =
            (f32x4){0.f, 0.f, 0.f, 0.f};
    }
    // k-pad cols [304,320) of rows 0..65: 66*2 = 132 16B slots (swizzled position)
    for (int i = tid; i < 132; i += NTHREADS) {
        const int row = i >> 1;
        const int byte = (row * XSTRIDE_B + 608 + (i & 1) * 16) ^ ((row & 7) << 4);
        *reinterpret_cast<f32x4*>(lds + byte) = (f32x4){0.f, 0.f, 0.f, 0.f};
    }

    // ---- 3) W fragments -> registers (A-operand; 1 k-of-t tile of 16 per wave)
    // frag: idx = lane&15 (W row = t col), k(d) = kk*32 + (lane>>4)*8 + i contiguous
    bf16x8 wfrag[10];
    {
        const int c = wv * 16 + lr;                     // W row 0..127
        const float* __restrict__ wr = W + c * ND;
#pragma unroll
        for (int kk = 0; kk < 10; ++kk) {
            const int k0 = kk * 32 + lg * 8;
            bf16x8 f = {0, 0, 0, 0, 0, 0, 0, 0};
            if (k0 < ND) {
                const float4 p0 = *reinterpret_cast<const float4*>(wr + k0);
                const float4 p1 = *reinterpret_cast<const float4*>(wr + k0 + 4);
                f[0] = f2bf(p0.x); f[1] = f2bf(p0.y);
                f[2] = f2bf(p0.z); f[3] = f2bf(p0.w);
                f[4] = f2bf(p1.x); f[5] = f2bf(p1.y);
                f[6] = f2bf(p1.z); f[7] = f2bf(p1.w);
            }
            wfrag[kk] = f;
        }
    }

    // ---- 4) convert + write stage-A to LDS (swizzled) ----
#pragma unroll
    for (int i = 0; i < 6; ++i) {
        const int e = tid + i * NTHREADS;
        if (e < 2640) {
            const int s = e / 40;
            const int f = (e % 40) * 4;                  // f32 col 0..156
            const int byte = (s * XSTRIDE_B + f * 2) ^ ((s & 7) << 4);
            s16x4 sv;
            sv[0] = f2bf(aA[i].x); sv[1] = f2bf(aA[i].y);
            sv[2] = f2bf(aA[i].z); sv[3] = f2bf(aA[i].w);
            *reinterpret_cast<s16x4*>(lds + byte) = sv;
        }
    }

    // ---- 5) issue stage-B global loads (x cols [160,304), 66*36=2376 float4) ----
    float4 aB[5];
#pragma unroll
    for (int i = 0; i < 5; ++i) {
        const int e = tid + i * NTHREADS;
        aB[i] = (e < 2376)
            ? *reinterpret_cast<const float4*>(xb + (e / 36) * ND + 160 + (e % 36) * 4)
            : make_float4(0.f, 0.f, 0.f, 0.f);
    }
    __syncthreads();

    // ---- 6) phase-1 first half: kk 0..4 (x cols [0,160)) ----
    f32x4 acc[5];
#pragma unroll
    for (int st = 0; st < 5; ++st) acc[st] = (f32x4){0.f, 0.f, 0.f, 0.f};

#pragma unroll
    for (int kk = 0; kk < 5; ++kk) {
        bf16x8 a[5];
#pragma unroll
        for (int st = 0; st < 5; ++st) {
            const int row = st * 16 + lr;
            const int byte = (row * XSTRIDE_B + kk * 64 + lg * 16) ^ ((row & 7) << 4);
            a[st] = *reinterpret_cast<const bf16x8*>(lds + byte);
        }
#pragma unroll
        for (int st = 0; st < 5; ++st)
            acc[st] = __builtin_amdgcn_mfma_f32_16x16x32_bf16(
                wfrag[kk], a[st], acc[st], 0, 0, 0);
    }

    // ---- 7) convert + write stage-B ----
#pragma unroll
    for (int i = 0; i < 5; ++i) {
        const int e = tid + i * NTHREADS;
        if (e < 2376) {
            const int s = e / 36;
            const int f = 160 + (e % 36) * 4;            // f32 col 160..300
            const int byte = (s * XSTRIDE_B + f * 2) ^ ((s & 7) << 4);
            s16x4 sv;
            sv[0] = f2bf(aB[i].x); sv[1] = f2bf(aB[i].y);
            sv[2] = f2bf(aB[i].z); sv[3] = f2bf(aB[i].w);
            *reinterpret_cast<s16x4*>(lds + byte) = sv;
        }
    }
    __syncthreads();

    // ---- 8) phase-1 second half: kk 5..9 ----
#pragma unroll
    for (int kk = 5; kk < 10; ++kk) {
        bf16x8 a[5];
#pragma unroll
        for (int st = 0; st < 5; ++st) {
            const int row = st * 16 + lr;
            const int byte = (row * XSTRIDE_B + kk * 64 + lg * 16) ^ ((row & 7) << 4);
            a[st] = *reinterpret_cast<const bf16x8*>(lds + byte);
        }
#pragma unroll
        for (int st = 0; st < 5; ++st)
            acc[st] = __builtin_amdgcn_mfma_f32_16x16x32_bf16(
                wfrag[kk], a[st], acc[st], 0, 0, 0);
    }

    // ---- 9) write t (bf16, swizzled, b64-packed) ----
    // swapped-operand D: col(lane&15) = s-in-tile, row(lg*4+r) = t-col-in-tile
    // => lane holds t[s][c0..c0+3], 4 consecutive cols -> one 8B write per s-tile
#pragma unroll
    for (int st = 0; st < 5; ++st) {
        const int s = st * 16 + lr;
        const int c0 = wv * 16 + lg * 4;
        const int byte = (s * TSTRIDE_B + c0 * 2) ^ ((s & 7) << 4);
        s16x4 sv;
        sv[0] = f2bf(acc[st][0]); sv[1] = f2bf(acc[st][1]);
        sv[2] = f2bf(acc[st][2]); sv[3] = f2bf(acc[st][3]);
        *reinterpret_cast<s16x4*>(t_lds + byte) = sv;
    }
    __syncthreads();

    // ---- 10) phase-2: 15 upper-triangle G tiles, held in registers ----
    const int idx0 = wv;            // waves 0..4 get the diagonal tiles
    const int idx1 = wv + 8;        // may be invalid for wv==7
    const int ti0 = TI_LUT[idx0], tj0 = TJ_LUT[idx0];

    f32x4 g0 = (f32x4){0.f, 0.f, 0.f, 0.f};
#pragma unroll
    for (int kk = 0; kk < 4; ++kk) {
        const int ra = ti0 * 16 + lr;
        const int ba = (ra * TSTRIDE_B + kk * 64 + lg * 16) ^ ((ra & 7) << 4);
        const int rb = tj0 * 16 + lr;
        const int bb = (rb * TSTRIDE_B + kk * 64 + lg * 16) ^ ((rb & 7) << 4);
        g0 = __builtin_amdgcn_mfma_f32_16x16x32_bf16(
            *reinterpret_cast<const bf16x8*>(t_lds + ba),
            *reinterpret_cast<const bf16x8*>(t_lds + bb), g0, 0, 0, 0);
    }
    // diagonal extraction: tile (wv,wv), element i==j where lr == lg*4+r
    if (wv < 5) {
#pragma unroll
        for (int r = 0; r < 4; ++r)
            if (lr == lg * 4 + r) norms[wv * 16 + lr] = g0[r];
    }

    f32x4 g1 = (f32x4){0.f, 0.f, 0.f, 0.f};
    int ti1 = 0, tj1 = 0;
    if (idx1 < 15) {
        ti1 = TI_LUT[idx1]; tj1 = TJ_LUT[idx1];
#pragma unroll
        for (int kk = 0; kk < 4; ++kk) {
            const int ra = ti1 * 16 + lr;
            const int ba = (ra * TSTRIDE_B + kk * 64 + lg * 16) ^ ((ra & 7) << 4);
            const int rb = tj1 * 16 + lr;
            const int bb = (rb * TSTRIDE_B + kk * 64 + lg * 16) ^ ((rb & 7) << 4);
            g1 = __builtin_amdgcn_mfma_f32_16x16x32_bf16(
                *reinterpret_cast<const bf16x8*>(t_lds + ba),
                *reinterpret_cast<const bf16x8*>(t_lds + bb), g1, 0, 0, 0);
        }
    }
    __syncthreads();

    // ---- 11) epilogue: out[i][j] = norms[i] + norms[j] - 2 G[i][j], + mirror ----
    float* __restrict__ ob = out + (size_t)batch * NS * NS;

    {   // tile 0 (always valid)
        const int j = tj0 * 16 + lr;
        const float nj = norms[j];
        float v[4];
#pragma unroll
        for (int r = 0; r < 4; ++r) {
            const int i = ti0 * 16 + lg * 4 + r;
            v[r] = norms[i] + nj - 2.f * g0[r];
            if (i < NS && j < NS) ob[i * NS + j] = v[r];
        }
        if (ti0 != tj0 && j < NS) {      // (never true for idx0<5, kept for safety)
#pragma unroll
            for (int r = 0; r < 4; ++r) {
                const int i = ti0 * 16 + lg * 4 + r;
                if (i < NS) ob[j * NS + i] = v[r];
            }
        }
    }
    if (idx1 < 15) {
        const int j = tj1 * 16 + lr;
        const float nj = norms[j];
        float v[4];
#pragma unroll
        for (int r = 0; r < 4; ++r) {
            const int i = ti1 * 16 + lg * 4 + r;
            v[r] = norms[i] + nj - 2.f * g1[r];
            if (i < NS && j < NS) ob[i * NS + j] = v[r];
        }
        if (j < NS) {                    // strict-upper: mirror write
#pragma unroll
            for (int r = 0; r < 4; ++r) {
                const int i = ti1 * 16 + lg * 4 + r;
                if (i < NS) ob[j * NS + i] = v[r];
            }
        }
    }
}

extern "C" void kernel_launch(void* const* d_in, const int* in_sizes, int n_in,
                              void* d_out, int out_size, void* d_ws, size_t ws_size,
                              hipStream_t stream) {
    const float* x = (const float*)d_in[0];   // (512, 66, 304) f32
    const float* W = (const float*)d_in[1];   // (128, 304) f32
    // d_in[2] = b : cancels in the pairwise difference, unused.
    float* out = (float*)d_out;               // (512, 66, 66) f32

    treeprobe_mfma<<<NBATCH, NTHREADS, 0, stream>>>(x, W, out);
}